// Round 3
// baseline (7533.089 us; speedup 1.0000x reference)
//
#include <hip/hip_runtime.h>
#include <math.h>

#define T_STEPS 64
#define BB 64
#define LL 2048
#define EE 128
#define HH 256
#define NCHUNK 16
#define LCHUNK (LL / NCHUNK) /* 128 */

__device__ __forceinline__ float fexp(float x) {
    return __builtin_amdgcn_exp2f(x * 1.44269504088896340736f);
}
__device__ __forceinline__ float fsig(float x) {
    return __builtin_amdgcn_rcpf(1.f + __builtin_amdgcn_exp2f(-1.44269504088896340736f * x));
}
__device__ __forceinline__ float ftanh(float x) {
    float xc = fminf(fmaxf(x, -20.f), 20.f);
    float p = __builtin_amdgcn_exp2f(2.885390081777926814f * xc); // e^{2x}
    return (p - 1.f) * __builtin_amdgcn_rcpf(p + 1.f);
}

// ---------------------------------------------------------------------------
// K1: attention for step t (= prev_t+1), fused with step-(t-1) epilogue
// (attns[prev_t] write + cov update) -- each block owns its (b, l-slice)
// exclusively, so the read-modify-write of cov is race-free.
// Wave = 4 row-subgroups x 16 h-chunks. Depth-1 software pipeline: next
// iteration's enc vectors + scalars are loaded while current row computes.
// Grid: NCHUNK*BB blocks, 256 threads.
// ---------------------------------------------------------------------------
__global__ __launch_bounds__(256, 4) void attn_kernel(
    const float* __restrict__ enc,   // (B,L,H)
    const float* __restrict__ mask,  // (B,L)
    float* __restrict__ cov,         // (B,L) in d_out, rmw
    const float* __restrict__ df,    // (B,H)
    const float* __restrict__ v,     // (H)
    const float* __restrict__ wc,    // (H)
    float* __restrict__ e_ws,        // (2,B,L) double buffer
    float* __restrict__ attns,       // (T,B,L)
    const float* __restrict__ m_ws,  // (B) prev-step max
    const float* __restrict__ is_ws, // (B) prev-step 1/S
    float* __restrict__ mp,          // (NCHUNK*B)
    float* __restrict__ sp,          // (NCHUNK*B)
    float* __restrict__ ctxp,        // (NCHUNK*B*H)
    int prev_t)
{
    const int g = blockIdx.x;
    const int b = g & (BB - 1);
    const int chunk = g >> 6;
    const int tid = threadIdx.x;
    const int wave = tid >> 6;
    const int lane = tid & 63;
    const int hc = lane & 15;
    const int lsub = lane >> 4;
    const int l0 = chunk * LCHUNK + wave * (LCHUNK / 4);
    const int t = prev_t + 1;

    const float* e_prev = e_ws + (size_t)(prev_t & 1) * BB * LL;
    float* e_cur = e_ws + (size_t)(t & 1) * BB * LL;
    float Mprev = 0.f, iSprev = 0.f;
    if (prev_t >= 0) { Mprev = m_ws[b]; iSprev = is_ws[b]; }

    float4 df4[4], v4[4], wc4[4];
    #pragma unroll
    for (int k = 0; k < 4; ++k) {
        const int h = hc * 4 + 64 * k;
        df4[k] = *(const float4*)(df + b * HH + h);
        v4[k]  = *(const float4*)(v + h);
        wc4[k] = *(const float4*)(wc + h);
    }

    const float4* ep0 = (const float4*)(enc + (size_t)(b * LL + l0 + lsub) * HH) + hc;

    // scalar stage: mask load, prev-step attn weight, coverage rmw
    auto scal = [&](int mi, float& cv, float& msk) {
        const int l = l0 + mi * 4 + lsub;
        const int idx = b * LL + l;
        msk = mask[idx];
        if (prev_t >= 0) {
            const float a = fexp(e_prev[idx] - Mprev) * msk * iSprev;
            cv = cov[idx] + a;
            if (hc == 0) {
                cov[idx] = cv;
                attns[((size_t)prev_t * BB + b) * LL + l] = a;
            }
        } else {
            cv = 0.f;
            if (hc == 0) cov[idx] = 0.f;
        }
    };

    float m = -INFINITY, s = 0.f;
    float4 cacc[4];
    #pragma unroll
    for (int k = 0; k < 4; ++k) cacc[k] = make_float4(0.f, 0.f, 0.f, 0.f);

    float cvA, mskA;
    float4 evA[4];
    scal(0, cvA, mskA);
    #pragma unroll
    for (int k = 0; k < 4; ++k) evA[k] = ep0[16 * k];

    #pragma unroll
    for (int mi = 0; mi < LCHUNK / 16; ++mi) {   // 8 iterations
        float cvB = 0.f, mskB = 0.f;
        float4 evB[4];
        if (mi < LCHUNK / 16 - 1) {
            scal(mi + 1, cvB, mskB);
            const float4* epn = ep0 + (mi + 1) * (HH / 4) * 4;
            #pragma unroll
            for (int k = 0; k < 4; ++k) evB[k] = epn[16 * k];
        }

        float p = 0.f;
        #pragma unroll
        for (int k = 0; k < 4; ++k) {
            const float t0 = ftanh(evA[k].x + df4[k].x + cvA * wc4[k].x);
            const float t1 = ftanh(evA[k].y + df4[k].y + cvA * wc4[k].y);
            const float t2 = ftanh(evA[k].z + df4[k].z + cvA * wc4[k].z);
            const float t3 = ftanh(evA[k].w + df4[k].w + cvA * wc4[k].w);
            p += v4[k].x * t0 + v4[k].y * t1 + v4[k].z * t2 + v4[k].w * t3;
        }
        p += __shfl_xor(p, 1);
        p += __shfl_xor(p, 2);
        p += __shfl_xor(p, 4);
        p += __shfl_xor(p, 8);
        const int l = l0 + mi * 4 + lsub;
        if (hc == 0) e_cur[b * LL + l] = p;

        const float mn = fmaxf(m, p);
        const float sc = fexp(m - mn);
        const float w  = fexp(p - mn) * mskA;
        s = s * sc + w;
        #pragma unroll
        for (int k = 0; k < 4; ++k) {
            cacc[k].x = cacc[k].x * sc + w * evA[k].x;
            cacc[k].y = cacc[k].y * sc + w * evA[k].y;
            cacc[k].z = cacc[k].z * sc + w * evA[k].z;
            cacc[k].w = cacc[k].w * sc + w * evA[k].w;
        }
        m = mn;
        cvA = cvB; mskA = mskB;
        #pragma unroll
        for (int k = 0; k < 4; ++k) evA[k] = evB[k];
    }

    // cross-subgroup butterfly (xor 16, 32) with max-rescale
    #pragma unroll
    for (int off = 16; off <= 32; off <<= 1) {
        const float m2 = __shfl_xor(m, off);
        const float s2 = __shfl_xor(s, off);
        const float mn = fmaxf(m, m2);
        const float wa = fexp(m - mn), wb = fexp(m2 - mn);
        s = s * wa + s2 * wb;
        #pragma unroll
        for (int k = 0; k < 4; ++k) {
            float4 c2;
            c2.x = __shfl_xor(cacc[k].x, off);
            c2.y = __shfl_xor(cacc[k].y, off);
            c2.z = __shfl_xor(cacc[k].z, off);
            c2.w = __shfl_xor(cacc[k].w, off);
            cacc[k].x = cacc[k].x * wa + c2.x * wb;
            cacc[k].y = cacc[k].y * wa + c2.y * wb;
            cacc[k].z = cacc[k].z * wa + c2.z * wb;
            cacc[k].w = cacc[k].w * wa + c2.w * wb;
        }
        m = mn;
    }

    __shared__ float lm[4], lsum[4];
    __shared__ float lctx[4][HH];
    if (lsub == 0) {
        #pragma unroll
        for (int k = 0; k < 4; ++k)
            *(float4*)&lctx[wave][hc * 4 + 64 * k] = cacc[k];
    }
    if (lane == 0) { lm[wave] = m; lsum[wave] = s; }
    __syncthreads();

    const float M = fmaxf(fmaxf(lm[0], lm[1]), fmaxf(lm[2], lm[3]));
    const float w0 = fexp(lm[0] - M), w1 = fexp(lm[1] - M),
                w2 = fexp(lm[2] - M), w3 = fexp(lm[3] - M);
    const int pidx = chunk * BB + b;
    ctxp[(size_t)pidx * HH + tid] =
        lctx[0][tid] * w0 + lctx[1][tid] * w1 + lctx[2][tid] * w2 + lctx[3][tid] * w3;
    if (tid == 0) {
        mp[pidx] = M;
        sp[pidx] = lsum[0] * w0 + lsum[1] * w1 + lsum[2] * w2 + lsum[3] * w3;
    }
}

// ---------------------------------------------------------------------------
// K2: per-step serial core. Grid BB blocks, 512 threads (8 waves).
// post_t >= 0: combine partials -> ctx, M, invS; out_t; pgen_t.
// post_t < 0: init carry (c,h from init; ctx=0).
// then (if pre_t=post_t+1 < T): x_{pre}, z, (c,h)_{pre}, dec_feat_{pre}.
// All K-loops are split across thread halves/quarters with LDS reduce.
// ---------------------------------------------------------------------------
__global__ __launch_bounds__(512) void step_kernel(
    const float* __restrict__ dec_in,
    const float* __restrict__ init_c,
    const float* __restrict__ init_h,
    const float* __restrict__ Wx, const float* __restrict__ bx,
    const float* __restrict__ Wl, const float* __restrict__ bl,
    const float* __restrict__ Ws, const float* __restrict__ bs,
    const float* __restrict__ Wp, const float* __restrict__ bp,
    const float* __restrict__ Wo, const float* __restrict__ bo,
    float* __restrict__ outs, float* __restrict__ c_out, float* __restrict__ h_out,
    float* __restrict__ pgens,
    const float* __restrict__ mp, const float* __restrict__ sp,
    const float* __restrict__ ctxp,
    float* __restrict__ m_ws, float* __restrict__ is_ws,
    float* __restrict__ x_ws, float* __restrict__ df_ws,
    int post_t)
{
    const int b = blockIdx.x;
    const int tid = threadIdx.x;
    const int pre_t = post_t + 1;
    __shared__ float sctx[HH], scv[HH], shv[HH], sxv[EE], siv[EE];
    __shared__ float zbuf[4][HH];
    __shared__ float red[8];

    if (post_t >= 0) {
        if (tid < HH) {
            scv[tid] = c_out[b * HH + tid];
            shv[tid] = h_out[b * HH + tid];
        }
        if (tid < EE) sxv[tid] = x_ws[b * EE + tid];
        // combine 16 chunk partials (threads 0..255, j = tid)
        if (tid < HH) {
            float M = -INFINITY;
            #pragma unroll
            for (int k = 0; k < NCHUNK; ++k) M = fmaxf(M, mp[k * BB + b]);
            float S = 0.f, cs = 0.f;
            #pragma unroll
            for (int k = 0; k < NCHUNK; ++k) {
                const float w = fexp(mp[k * BB + b] - M);
                S += sp[k * BB + b] * w;
                cs += ctxp[(size_t)(k * BB + b) * HH + tid] * w;
            }
            const float invS = 1.f / S;
            sctx[tid] = cs * invS;
            if (tid == 0) { m_ws[b] = M; is_ws[b] = invS; }
        }
        __syncthreads();

        // out_t = [h, ctx] @ W_o + b_o : j = tid&255, half = tid>>8, K=256 each
        {
            const int j = tid & 255, half = tid >> 8;
            const float* src = half ? sctx : shv;
            const float* wcol = Wo + (size_t)(half * HH) * HH + j;
            float a0 = 0.f, a1 = 0.f;
            #pragma unroll 4
            for (int r = 0; r < 128; ++r) {
                a0 += src[r] * wcol[(size_t)r * HH];
                a1 += src[r + 128] * wcol[(size_t)(r + 128) * HH];
            }
            if (half) zbuf[0][j] = a0 + a1;
            __syncthreads();
            if (!half)
                outs[((size_t)post_t * BB + b) * HH + j] = a0 + a1 + zbuf[0][j] + bo[j];
        }

        // pgen_t = sigmoid([ctx, c, h, x] @ W_p + b_p)
        {
            float pp = (tid < 256 ? sctx[tid] : scv[tid - 256]) * Wp[tid];
            if (tid < 256) pp += shv[tid] * Wp[tid + 512];
            else if (tid < 384) pp += sxv[tid - 256] * Wp[tid + 512];
            #pragma unroll
            for (int off = 32; off; off >>= 1) pp += __shfl_xor(pp, off);
            if ((tid & 63) == 0) red[tid >> 6] = pp;
            __syncthreads();
            if (tid == 0) {
                float acc = bp[0];
                #pragma unroll
                for (int k = 0; k < 8; ++k) acc += red[k];
                pgens[(size_t)post_t * BB + b] = fsig(acc);
            }
        }
    } else {
        if (tid < HH) {
            scv[tid] = init_c[b * HH + tid];
            shv[tid] = init_h[b * HH + tid];
            sctx[tid] = 0.f;
        }
        __syncthreads();
        __syncthreads();   // keep barrier count uniform-ish (block-uniform branch, safe anyway)
    }

    if (pre_t < T_STEPS) {
        if (tid < EE) siv[tid] = dec_in[((size_t)pre_t * BB + b) * EE + tid];
        __syncthreads();   // guards siv write + sxv overwrite vs pgen reads

        // x = relu([inp, ctx] @ W_x + b_x): j = tid&127, q = tid>>7, K=96
        {
            const int j = tid & 127, q = tid >> 7;
            const int r0 = q * 96;
            float a0 = 0.f;
            for (int r = r0; r < r0 + 96; ++r) {
                const float f = (r < EE) ? siv[r] : sctx[r - EE];
                a0 += f * Wx[(size_t)r * EE + j];
            }
            if (q) zbuf[q][j] = a0;
            __syncthreads();
            if (q == 0) {
                const float xv = fmaxf(a0 + zbuf[1][j] + zbuf[2][j] + zbuf[3][j] + bx[j], 0.f);
                sxv[j] = xv;
                x_ws[b * EE + j] = xv;
            }
            __syncthreads();
        }

        // z = [x, h] @ W_lstm + b_lstm: u = tid&255, gate pair gp = tid>>8
        {
            const int u = tid & 255, gp = tid >> 8;
            const int c0 = gp * 512 + u, c1 = gp * 512 + 256 + u;
            float za0 = bl[c0], za1 = 0.f, zb0 = bl[c1], zb1 = 0.f;
            #pragma unroll 2
            for (int r = 0; r < 192; ++r) {
                const float f0 = (r < EE) ? sxv[r] : shv[r - EE];
                const float f1 = shv[r + 64];                 // rows 192..383 are all h
                za0 += f0 * Wl[(size_t)r * 1024 + c0];
                za1 += f1 * Wl[(size_t)(r + 192) * 1024 + c0];
                zb0 += f0 * Wl[(size_t)r * 1024 + c1];
                zb1 += f1 * Wl[(size_t)(r + 192) * 1024 + c1];
            }
            zbuf[gp * 2][u] = za0 + za1;
            zbuf[gp * 2 + 1][u] = zb0 + zb1;
            __syncthreads();
        }

        // c, h update (threads 0..255)
        if (tid < HH) {
            const float zi = zbuf[0][tid], zf = zbuf[1][tid],
                        zg = zbuf[2][tid], zo = zbuf[3][tid];
            const float cn = fsig(zf) * scv[tid] + fsig(zi) * ftanh(zg);
            const float hn = fsig(zo) * ftanh(cn);
            c_out[b * HH + tid] = cn;
            h_out[b * HH + tid] = hn;
            scv[tid] = cn;
            shv[tid] = hn;
        }
        __syncthreads();

        // dec_feat = tanh([c, h] @ W_s + b_s): j = tid&255, half = tid>>8
        {
            const int j = tid & 255, half = tid >> 8;
            const float* src = half ? shv : scv;
            const float* wcol = Ws + (size_t)(half * HH) * HH + j;
            float a0 = 0.f, a1 = 0.f;
            #pragma unroll 4
            for (int r = 0; r < 128; ++r) {
                a0 += src[r] * wcol[(size_t)r * HH];
                a1 += src[r + 128] * wcol[(size_t)(r + 128) * HH];
            }
            if (half) zbuf[0][j] = a0 + a1;
            __syncthreads();
            if (!half) df_ws[b * HH + j] = ftanh(a0 + a1 + zbuf[0][j] + bs[j]);
        }
    }
}

// ---------------------------------------------------------------------------
// Final epilogue: attns[T-1] and cov += a_{T-1}. Grid BB, 256 threads.
// ---------------------------------------------------------------------------
__global__ __launch_bounds__(256) void epi_kernel(
    const float* __restrict__ e_ws, const float* __restrict__ mask,
    const float* __restrict__ m_ws, const float* __restrict__ is_ws,
    float* __restrict__ attns, float* __restrict__ cov)
{
    const int b = blockIdx.x;
    const int j = threadIdx.x;
    const float Mp = m_ws[b], iS = is_ws[b];
    const float* e_last = e_ws + (size_t)((T_STEPS - 1) & 1) * BB * LL;
    for (int i = 0; i < LL / 256; ++i) {
        const int l = i * 256 + j;
        const int idx = b * LL + l;
        const float a = fexp(e_last[idx] - Mp) * mask[idx] * iS;
        attns[((size_t)(T_STEPS - 1) * BB + b) * LL + l] = a;
        cov[idx] += a;
    }
}

extern "C" void kernel_launch(void* const* d_in, const int* in_sizes, int n_in,
                              void* d_out, int out_size, void* d_ws, size_t ws_size,
                              hipStream_t stream) {
    const float* dec_in = (const float*)d_in[0];
    const float* init_c = (const float*)d_in[1];
    const float* init_h = (const float*)d_in[2];
    const float* enc    = (const float*)d_in[3];
    const float* mask   = (const float*)d_in[4];
    const float* Wx = (const float*)d_in[5];
    const float* bx = (const float*)d_in[6];
    const float* Wl = (const float*)d_in[7];
    const float* bl = (const float*)d_in[8];
    const float* Ws = (const float*)d_in[9];
    const float* bs = (const float*)d_in[10];
    const float* v  = (const float*)d_in[11];
    const float* wc = (const float*)d_in[12];
    const float* Wp = (const float*)d_in[13];
    const float* bp = (const float*)d_in[14];
    const float* Wo = (const float*)d_in[15];
    const float* bo = (const float*)d_in[16];

    float* out   = (float*)d_out;
    float* outs  = out;                                   // T*B*H
    float* c_out = outs + (size_t)T_STEPS * BB * HH;      // B*H
    float* h_out = c_out + BB * HH;                       // B*H
    float* attns = h_out + BB * HH;                       // T*B*L
    float* pgens = attns + (size_t)T_STEPS * BB * LL;     // T*B
    float* cov   = pgens + T_STEPS * BB;                  // B*L

    float* ws    = (float*)d_ws;
    float* e_ws  = ws;                                    // 2*B*L
    float* mp    = e_ws + 2 * BB * LL;                    // NCHUNK*B
    float* sp    = mp + NCHUNK * BB;                      // NCHUNK*B
    float* ctxp  = sp + NCHUNK * BB;                      // NCHUNK*B*H
    float* x_ws  = ctxp + (size_t)NCHUNK * BB * HH;       // B*E
    float* df_ws = x_ws + BB * EE;                        // B*H
    float* m_ws  = df_ws + BB * HH;                       // B
    float* is_ws = m_ws + BB;                             // B

    // init: A_0 (x_0, c_0, h_0, dec_feat_0), ctx = 0
    step_kernel<<<BB, 512, 0, stream>>>(dec_in, init_c, init_h,
        Wx, bx, Wl, bl, Ws, bs, Wp, bp, Wo, bo,
        outs, c_out, h_out, pgens, mp, sp, ctxp, m_ws, is_ws, x_ws, df_ws, -1);

    for (int t = 0; t < T_STEPS; ++t) {
        attn_kernel<<<NCHUNK * BB, 256, 0, stream>>>(
            enc, mask, cov, df_ws, v, wc, e_ws, attns, m_ws, is_ws,
            mp, sp, ctxp, t - 1);
        step_kernel<<<BB, 512, 0, stream>>>(dec_in, init_c, init_h,
            Wx, bx, Wl, bl, Ws, bs, Wp, bp, Wo, bo,
            outs, c_out, h_out, pgens, mp, sp, ctxp, m_ws, is_ws, x_ws, df_ws, t);
    }

    epi_kernel<<<BB, 256, 0, stream>>>(e_ws, mask, m_ws, is_ws, attns, cov);
}

// Round 4
// 5668.089 us; speedup vs baseline: 1.3290x; 1.3290x over previous
//
#include <hip/hip_runtime.h>
#include <math.h>

#define T_STEPS 64
#define BB 64
#define LL 2048
#define EE 128
#define HH 256
#define NCHUNK 32
#define LCHUNK (LL / NCHUNK) /* 64 */

__device__ __forceinline__ float fexp(float x) {
    return __builtin_amdgcn_exp2f(x * 1.44269504088896340736f);
}
__device__ __forceinline__ float fsig(float x) {
    return __builtin_amdgcn_rcpf(1.f + __builtin_amdgcn_exp2f(-1.44269504088896340736f * x));
}
__device__ __forceinline__ float ftanh(float x) {
    float xc = fminf(fmaxf(x, -20.f), 20.f);
    float p = __builtin_amdgcn_exp2f(2.885390081777926814f * xc); // e^{2x}
    return (p - 1.f) * __builtin_amdgcn_rcpf(p + 1.f);
}

// ---------------------------------------------------------------------------
// K1: attention for step t (= prev_t+1), fused with step-(t-1) epilogue
// (attns[prev_t] write + cov update). Each block owns its (b, l-slice)
// exclusively -> race-free cov rmw. Wave = 4 row-subgroups x 16 h-chunks,
// depth-1 software pipeline. NO register cap (r3's launch_bounds(256,4)
// forced VGPR=64 -> 88MB/dispatch scratch spills).
// Grid: NCHUNK*BB = 2048 blocks, 256 threads.
// ---------------------------------------------------------------------------
__global__ __launch_bounds__(256) void attn_kernel(
    const float* __restrict__ enc,   // (B,L,H)
    const float* __restrict__ mask,  // (B,L)
    float* __restrict__ cov,         // (B,L) in d_out, rmw
    const float* __restrict__ df,    // (B,H)
    const float* __restrict__ v,     // (H)
    const float* __restrict__ wc,    // (H)
    float* __restrict__ e_ws,        // (2,B,L) double buffer
    float* __restrict__ attns,       // (T,B,L)
    const float* __restrict__ m_ws,  // (B) prev-step max
    const float* __restrict__ is_ws, // (B) prev-step 1/S
    float* __restrict__ mp,          // (NCHUNK*B)
    float* __restrict__ sp,          // (NCHUNK*B)
    float* __restrict__ ctxp,        // (NCHUNK*B*H)
    int prev_t)
{
    const int g = blockIdx.x;
    const int b = g & (BB - 1);
    const int chunk = g >> 6;
    const int tid = threadIdx.x;
    const int wave = tid >> 6;
    const int lane = tid & 63;
    const int hc = lane & 15;
    const int lsub = lane >> 4;
    const int l0 = chunk * LCHUNK + wave * (LCHUNK / 4);
    const int t = prev_t + 1;

    const float* e_prev = e_ws + (size_t)(prev_t & 1) * BB * LL;
    float* e_cur = e_ws + (size_t)(t & 1) * BB * LL;
    float Mprev = 0.f, iSprev = 0.f;
    if (prev_t >= 0) { Mprev = m_ws[b]; iSprev = is_ws[b]; }

    float4 df4[4], v4[4], wc4[4];
    #pragma unroll
    for (int k = 0; k < 4; ++k) {
        const int h = hc * 4 + 64 * k;
        df4[k] = *(const float4*)(df + b * HH + h);
        v4[k]  = *(const float4*)(v + h);
        wc4[k] = *(const float4*)(wc + h);
    }

    const float4* ep0 = (const float4*)(enc + (size_t)(b * LL + l0 + lsub) * HH) + hc;

    // scalar stage: mask load, prev-step attn weight, coverage rmw
    auto scal = [&](int mi, float& cv, float& msk) {
        const int l = l0 + mi * 4 + lsub;
        const int idx = b * LL + l;
        msk = mask[idx];
        if (prev_t >= 0) {
            const float a = fexp(e_prev[idx] - Mprev) * msk * iSprev;
            cv = cov[idx] + a;
            if (hc == 0) {
                cov[idx] = cv;
                attns[((size_t)prev_t * BB + b) * LL + l] = a;
            }
        } else {
            cv = 0.f;
            if (hc == 0) cov[idx] = 0.f;
        }
    };

    float m = -INFINITY, s = 0.f;
    float4 cacc[4];
    #pragma unroll
    for (int k = 0; k < 4; ++k) cacc[k] = make_float4(0.f, 0.f, 0.f, 0.f);

    float cvA, mskA;
    float4 evA[4];
    scal(0, cvA, mskA);
    #pragma unroll
    for (int k = 0; k < 4; ++k) evA[k] = ep0[16 * k];

    #pragma unroll
    for (int mi = 0; mi < LCHUNK / 16; ++mi) {   // 4 iterations
        float cvB = 0.f, mskB = 0.f;
        float4 evB[4];
        if (mi < LCHUNK / 16 - 1) {
            scal(mi + 1, cvB, mskB);
            const float4* epn = ep0 + (mi + 1) * (HH / 4) * 4;
            #pragma unroll
            for (int k = 0; k < 4; ++k) evB[k] = epn[16 * k];
        }

        float p = 0.f;
        #pragma unroll
        for (int k = 0; k < 4; ++k) {
            const float t0 = ftanh(evA[k].x + df4[k].x + cvA * wc4[k].x);
            const float t1 = ftanh(evA[k].y + df4[k].y + cvA * wc4[k].y);
            const float t2 = ftanh(evA[k].z + df4[k].z + cvA * wc4[k].z);
            const float t3 = ftanh(evA[k].w + df4[k].w + cvA * wc4[k].w);
            p += v4[k].x * t0 + v4[k].y * t1 + v4[k].z * t2 + v4[k].w * t3;
        }
        p += __shfl_xor(p, 1);
        p += __shfl_xor(p, 2);
        p += __shfl_xor(p, 4);
        p += __shfl_xor(p, 8);
        const int l = l0 + mi * 4 + lsub;
        if (hc == 0) e_cur[b * LL + l] = p;

        const float mn = fmaxf(m, p);
        const float sc = fexp(m - mn);
        const float w  = fexp(p - mn) * mskA;
        s = s * sc + w;
        #pragma unroll
        for (int k = 0; k < 4; ++k) {
            cacc[k].x = cacc[k].x * sc + w * evA[k].x;
            cacc[k].y = cacc[k].y * sc + w * evA[k].y;
            cacc[k].z = cacc[k].z * sc + w * evA[k].z;
            cacc[k].w = cacc[k].w * sc + w * evA[k].w;
        }
        m = mn;
        cvA = cvB; mskA = mskB;
        #pragma unroll
        for (int k = 0; k < 4; ++k) evA[k] = evB[k];
    }

    // cross-subgroup butterfly (xor 16, 32) with max-rescale
    #pragma unroll
    for (int off = 16; off <= 32; off <<= 1) {
        const float m2 = __shfl_xor(m, off);
        const float s2 = __shfl_xor(s, off);
        const float mn = fmaxf(m, m2);
        const float wa = fexp(m - mn), wb = fexp(m2 - mn);
        s = s * wa + s2 * wb;
        #pragma unroll
        for (int k = 0; k < 4; ++k) {
            float4 c2;
            c2.x = __shfl_xor(cacc[k].x, off);
            c2.y = __shfl_xor(cacc[k].y, off);
            c2.z = __shfl_xor(cacc[k].z, off);
            c2.w = __shfl_xor(cacc[k].w, off);
            cacc[k].x = cacc[k].x * wa + c2.x * wb;
            cacc[k].y = cacc[k].y * wa + c2.y * wb;
            cacc[k].z = cacc[k].z * wa + c2.z * wb;
            cacc[k].w = cacc[k].w * wa + c2.w * wb;
        }
        m = mn;
    }

    __shared__ float lm[4], lsum[4];
    __shared__ float lctx[4][HH];
    if (lsub == 0) {
        #pragma unroll
        for (int k = 0; k < 4; ++k)
            *(float4*)&lctx[wave][hc * 4 + 64 * k] = cacc[k];
    }
    if (lane == 0) { lm[wave] = m; lsum[wave] = s; }
    __syncthreads();

    const float M = fmaxf(fmaxf(lm[0], lm[1]), fmaxf(lm[2], lm[3]));
    const float w0 = fexp(lm[0] - M), w1 = fexp(lm[1] - M),
                w2 = fexp(lm[2] - M), w3 = fexp(lm[3] - M);
    const int pidx = chunk * BB + b;
    ctxp[(size_t)pidx * HH + tid] =
        lctx[0][tid] * w0 + lctx[1][tid] * w1 + lctx[2][tid] * w2 + lctx[3][tid] * w3;
    if (tid == 0) {
        mp[pidx] = M;
        sp[pidx] = lsum[0] * w0 + lsum[1] * w1 + lsum[2] * w2 + lsum[3] * w3;
    }
}

// ---------------------------------------------------------------------------
// K2: per-step serial core. Grid BB blocks, 512 threads (8 waves).
// ---------------------------------------------------------------------------
__global__ __launch_bounds__(512) void step_kernel(
    const float* __restrict__ dec_in,
    const float* __restrict__ init_c,
    const float* __restrict__ init_h,
    const float* __restrict__ Wx, const float* __restrict__ bx,
    const float* __restrict__ Wl, const float* __restrict__ bl,
    const float* __restrict__ Ws, const float* __restrict__ bs,
    const float* __restrict__ Wp, const float* __restrict__ bp,
    const float* __restrict__ Wo, const float* __restrict__ bo,
    float* __restrict__ outs, float* __restrict__ c_out, float* __restrict__ h_out,
    float* __restrict__ pgens,
    const float* __restrict__ mp, const float* __restrict__ sp,
    const float* __restrict__ ctxp,
    float* __restrict__ m_ws, float* __restrict__ is_ws,
    float* __restrict__ x_ws, float* __restrict__ df_ws,
    int post_t)
{
    const int b = blockIdx.x;
    const int tid = threadIdx.x;
    const int pre_t = post_t + 1;
    __shared__ float sctx[HH], scv[HH], shv[HH], sxv[EE], siv[EE];
    __shared__ float zbuf[4][HH];
    __shared__ float red[8];

    if (post_t >= 0) {
        if (tid < HH) {
            scv[tid] = c_out[b * HH + tid];
            shv[tid] = h_out[b * HH + tid];
        }
        if (tid < EE) sxv[tid] = x_ws[b * EE + tid];
        if (tid < HH) {
            float M = -INFINITY;
            #pragma unroll
            for (int k = 0; k < NCHUNK; ++k) M = fmaxf(M, mp[k * BB + b]);
            float S = 0.f, cs = 0.f;
            #pragma unroll
            for (int k = 0; k < NCHUNK; ++k) {
                const float w = fexp(mp[k * BB + b] - M);
                S += sp[k * BB + b] * w;
                cs += ctxp[(size_t)(k * BB + b) * HH + tid] * w;
            }
            const float invS = 1.f / S;
            sctx[tid] = cs * invS;
            if (tid == 0) { m_ws[b] = M; is_ws[b] = invS; }
        }
        __syncthreads();

        // out_t = [h, ctx] @ W_o + b_o : j = tid&255, half = tid>>8
        {
            const int j = tid & 255, half = tid >> 8;
            const float* src = half ? sctx : shv;
            const float* wcol = Wo + (size_t)(half * HH) * HH + j;
            float a0 = 0.f, a1 = 0.f;
            #pragma unroll 4
            for (int r = 0; r < 128; ++r) {
                a0 += src[r] * wcol[(size_t)r * HH];
                a1 += src[r + 128] * wcol[(size_t)(r + 128) * HH];
            }
            if (half) zbuf[0][j] = a0 + a1;
            __syncthreads();
            if (!half)
                outs[((size_t)post_t * BB + b) * HH + j] = a0 + a1 + zbuf[0][j] + bo[j];
        }

        // pgen_t = sigmoid([ctx, c, h, x] @ W_p + b_p)
        {
            float pp = (tid < 256 ? sctx[tid] : scv[tid - 256]) * Wp[tid];
            if (tid < 256) pp += shv[tid] * Wp[tid + 512];
            else if (tid < 384) pp += sxv[tid - 256] * Wp[tid + 512];
            #pragma unroll
            for (int off = 32; off; off >>= 1) pp += __shfl_xor(pp, off);
            if ((tid & 63) == 0) red[tid >> 6] = pp;
            __syncthreads();
            if (tid == 0) {
                float acc = bp[0];
                #pragma unroll
                for (int k = 0; k < 8; ++k) acc += red[k];
                pgens[(size_t)post_t * BB + b] = fsig(acc);
            }
        }
    } else {
        if (tid < HH) {
            scv[tid] = init_c[b * HH + tid];
            shv[tid] = init_h[b * HH + tid];
            sctx[tid] = 0.f;
        }
        __syncthreads();
        __syncthreads();
    }

    if (pre_t < T_STEPS) {
        if (tid < EE) siv[tid] = dec_in[((size_t)pre_t * BB + b) * EE + tid];
        __syncthreads();

        // x = relu([inp, ctx] @ W_x + b_x): j = tid&127, q = tid>>7, K=96
        {
            const int j = tid & 127, q = tid >> 7;
            const int r0 = q * 96;
            float a0 = 0.f;
            for (int r = r0; r < r0 + 96; ++r) {
                const float f = (r < EE) ? siv[r] : sctx[r - EE];
                a0 += f * Wx[(size_t)r * EE + j];
            }
            if (q) zbuf[q][j] = a0;
            __syncthreads();
            if (q == 0) {
                const float xv = fmaxf(a0 + zbuf[1][j] + zbuf[2][j] + zbuf[3][j] + bx[j], 0.f);
                sxv[j] = xv;
                x_ws[b * EE + j] = xv;
            }
            __syncthreads();
        }

        // z = [x, h] @ W_lstm + b_lstm: u = tid&255, gate pair gp = tid>>8
        {
            const int u = tid & 255, gp = tid >> 8;
            const int c0 = gp * 512 + u, c1 = gp * 512 + 256 + u;
            float za0 = bl[c0], za1 = 0.f, zb0 = bl[c1], zb1 = 0.f;
            #pragma unroll 2
            for (int r = 0; r < 192; ++r) {
                const float f0 = (r < EE) ? sxv[r] : shv[r - EE];
                const float f1 = shv[r + 64];
                za0 += f0 * Wl[(size_t)r * 1024 + c0];
                za1 += f1 * Wl[(size_t)(r + 192) * 1024 + c0];
                zb0 += f0 * Wl[(size_t)r * 1024 + c1];
                zb1 += f1 * Wl[(size_t)(r + 192) * 1024 + c1];
            }
            zbuf[gp * 2][u] = za0 + za1;
            zbuf[gp * 2 + 1][u] = zb0 + zb1;
            __syncthreads();
        }

        if (tid < HH) {
            const float zi = zbuf[0][tid], zf = zbuf[1][tid],
                        zg = zbuf[2][tid], zo = zbuf[3][tid];
            const float cn = fsig(zf) * scv[tid] + fsig(zi) * ftanh(zg);
            const float hn = fsig(zo) * ftanh(cn);
            c_out[b * HH + tid] = cn;
            h_out[b * HH + tid] = hn;
            scv[tid] = cn;
            shv[tid] = hn;
        }
        __syncthreads();

        // dec_feat = tanh([c, h] @ W_s + b_s)
        {
            const int j = tid & 255, half = tid >> 8;
            const float* src = half ? shv : scv;
            const float* wcol = Ws + (size_t)(half * HH) * HH + j;
            float a0 = 0.f, a1 = 0.f;
            #pragma unroll 4
            for (int r = 0; r < 128; ++r) {
                a0 += src[r] * wcol[(size_t)r * HH];
                a1 += src[r + 128] * wcol[(size_t)(r + 128) * HH];
            }
            if (half) zbuf[0][j] = a0 + a1;
            __syncthreads();
            if (!half) df_ws[b * HH + j] = ftanh(a0 + a1 + zbuf[0][j] + bs[j]);
        }
    }
}

// ---------------------------------------------------------------------------
// Final epilogue: attns[T-1] and cov += a_{T-1}. Grid BB, 256 threads.
// ---------------------------------------------------------------------------
__global__ __launch_bounds__(256) void epi_kernel(
    const float* __restrict__ e_ws, const float* __restrict__ mask,
    const float* __restrict__ m_ws, const float* __restrict__ is_ws,
    float* __restrict__ attns, float* __restrict__ cov)
{
    const int b = blockIdx.x;
    const int j = threadIdx.x;
    const float Mp = m_ws[b], iS = is_ws[b];
    const float* e_last = e_ws + (size_t)((T_STEPS - 1) & 1) * BB * LL;
    for (int i = 0; i < LL / 256; ++i) {
        const int l = i * 256 + j;
        const int idx = b * LL + l;
        const float a = fexp(e_last[idx] - Mp) * mask[idx] * iS;
        attns[((size_t)(T_STEPS - 1) * BB + b) * LL + l] = a;
        cov[idx] += a;
    }
}

extern "C" void kernel_launch(void* const* d_in, const int* in_sizes, int n_in,
                              void* d_out, int out_size, void* d_ws, size_t ws_size,
                              hipStream_t stream) {
    const float* dec_in = (const float*)d_in[0];
    const float* init_c = (const float*)d_in[1];
    const float* init_h = (const float*)d_in[2];
    const float* enc    = (const float*)d_in[3];
    const float* mask   = (const float*)d_in[4];
    const float* Wx = (const float*)d_in[5];
    const float* bx = (const float*)d_in[6];
    const float* Wl = (const float*)d_in[7];
    const float* bl = (const float*)d_in[8];
    const float* Ws = (const float*)d_in[9];
    const float* bs = (const float*)d_in[10];
    const float* v  = (const float*)d_in[11];
    const float* wc = (const float*)d_in[12];
    const float* Wp = (const float*)d_in[13];
    const float* bp = (const float*)d_in[14];
    const float* Wo = (const float*)d_in[15];
    const float* bo = (const float*)d_in[16];

    float* out   = (float*)d_out;
    float* outs  = out;                                   // T*B*H
    float* c_out = outs + (size_t)T_STEPS * BB * HH;      // B*H
    float* h_out = c_out + BB * HH;                       // B*H
    float* attns = h_out + BB * HH;                       // T*B*L
    float* pgens = attns + (size_t)T_STEPS * BB * LL;     // T*B
    float* cov   = pgens + T_STEPS * BB;                  // B*L

    float* ws    = (float*)d_ws;
    float* e_ws  = ws;                                    // 2*B*L
    float* mp    = e_ws + 2 * BB * LL;                    // NCHUNK*B
    float* sp    = mp + NCHUNK * BB;                      // NCHUNK*B
    float* ctxp  = sp + NCHUNK * BB;                      // NCHUNK*B*H
    float* x_ws  = ctxp + (size_t)NCHUNK * BB * HH;       // B*E
    float* df_ws = x_ws + BB * EE;                        // B*H
    float* m_ws  = df_ws + BB * HH;                       // B
    float* is_ws = m_ws + BB;                             // B

    step_kernel<<<BB, 512, 0, stream>>>(dec_in, init_c, init_h,
        Wx, bx, Wl, bl, Ws, bs, Wp, bp, Wo, bo,
        outs, c_out, h_out, pgens, mp, sp, ctxp, m_ws, is_ws, x_ws, df_ws, -1);

    for (int t = 0; t < T_STEPS; ++t) {
        attn_kernel<<<NCHUNK * BB, 256, 0, stream>>>(
            enc, mask, cov, df_ws, v, wc, e_ws, attns, m_ws, is_ws,
            mp, sp, ctxp, t - 1);
        step_kernel<<<BB, 512, 0, stream>>>(dec_in, init_c, init_h,
            Wx, bx, Wl, bl, Ws, bs, Wp, bp, Wo, bo,
            outs, c_out, h_out, pgens, mp, sp, ctxp, m_ws, is_ws, x_ws, df_ws, t);
    }

    epi_kernel<<<BB, 256, 0, stream>>>(e_ws, mask, m_ws, is_ws, attns, cov);
}

// Round 5
// 4385.859 us; speedup vs baseline: 1.7176x; 1.2924x over previous
//
#include <hip/hip_runtime.h>
#include <math.h>

#define T_STEPS 64
#define BB 64
#define LL 2048
#define EE 128
#define HH 256
#define NCHUNK 32
#define LCHUNK (LL / NCHUNK) /* 64 */

__device__ __forceinline__ float fexp(float x) {
    return __builtin_amdgcn_exp2f(x * 1.44269504088896340736f);
}
__device__ __forceinline__ float fsig(float x) {
    return __builtin_amdgcn_rcpf(1.f + __builtin_amdgcn_exp2f(-1.44269504088896340736f * x));
}
__device__ __forceinline__ float ftanh(float x) {
    float xc = fminf(fmaxf(x, -20.f), 20.f);
    float p = __builtin_amdgcn_exp2f(2.885390081777926814f * xc); // e^{2x}
    return (p - 1.f) * __builtin_amdgcn_rcpf(p + 1.f);
}
// round-to-nearest-even fp32 -> bf16 (as u16 in low bits)
__device__ __forceinline__ unsigned int bfr(float x) {
    unsigned int u = __float_as_uint(x);
    return (u + 0x7FFFu + ((u >> 16) & 1u)) >> 16;
}
__device__ __forceinline__ void bf8x(const uint4 q, float* f) {
    f[0] = __uint_as_float(q.x << 16); f[1] = __uint_as_float(q.x & 0xFFFF0000u);
    f[2] = __uint_as_float(q.y << 16); f[3] = __uint_as_float(q.y & 0xFFFF0000u);
    f[4] = __uint_as_float(q.z << 16); f[5] = __uint_as_float(q.z & 0xFFFF0000u);
    f[6] = __uint_as_float(q.w << 16); f[7] = __uint_as_float(q.w & 0xFFFF0000u);
}
__device__ __forceinline__ void load8(const float* p, float* d) {
    float4 a = *(const float4*)p, b = *(const float4*)(p + 4);
    d[0]=a.x; d[1]=a.y; d[2]=a.z; d[3]=a.w; d[4]=b.x; d[5]=b.y; d[6]=b.z; d[7]=b.w;
}

// ---------------------------------------------------------------------------
// K0: one-time fp32 -> bf16 conversion of enc (RNE).
// ---------------------------------------------------------------------------
__global__ __launch_bounds__(256) void conv_kernel(
    const float4* __restrict__ enc, uint4* __restrict__ encb)
{
    const int n = BB * LL * HH / 8;
    for (int i = blockIdx.x * 256 + threadIdx.x; i < n; i += gridDim.x * 256) {
        const float4 a = enc[2 * i], c = enc[2 * i + 1];
        uint4 o;
        o.x = bfr(a.x) | (bfr(a.y) << 16);
        o.y = bfr(a.z) | (bfr(a.w) << 16);
        o.z = bfr(c.x) | (bfr(c.y) << 16);
        o.w = bfr(c.z) | (bfr(c.w) << 16);
        encb[i] = o;
    }
}

// ---------------------------------------------------------------------------
// K1: attention pass for step t (bf16 enc), fused with step-(t-1) epilogue
// (attns[t-1] write + cov rmw; block owns its (b,l-slice) -> race-free).
// Wave = 4 row-subgroups x 16 h-chunks; each lane covers 16 h-elems
// (h = hc*8 + 128k + j). Depth-1 prefetch of next row's enc/scalars.
// Grid: NCHUNK*BB = 2048 blocks, 256 threads.
// ---------------------------------------------------------------------------
__global__ __launch_bounds__(256) void attn_kernel(
    const uint4* __restrict__ encb,  // (B*L, 32) uint4 (=256 bf16 per row)
    const float* __restrict__ mask,
    float* __restrict__ cov,
    const float* __restrict__ df,
    const float* __restrict__ v,
    const float* __restrict__ wc,
    float* __restrict__ e_ws,        // (2,B,L)
    float* __restrict__ attns,
    const float* __restrict__ m_ws,
    const float* __restrict__ is_ws,
    float* __restrict__ mp, float* __restrict__ sp, float* __restrict__ ctxp,
    int t)
{
    const int prev_t = t - 1;
    const int g = blockIdx.x;
    const int b = g & (BB - 1);
    const int chunk = g >> 6;
    const int tid = threadIdx.x;
    const int wave = tid >> 6;
    const int lane = tid & 63;
    const int hc = lane & 15;
    const int lsub = lane >> 4;
    const int l0 = chunk * LCHUNK + wave * (LCHUNK / 4);

    const float* e_prev = e_ws + (size_t)(prev_t & 1) * BB * LL;
    float* e_cur = e_ws + (size_t)(t & 1) * BB * LL;
    float Mprev = 0.f, iSprev = 0.f;
    if (prev_t >= 0) { Mprev = m_ws[b]; iSprev = is_ws[b]; }

    float dfv[16], vv[16], wcv[16];
    #pragma unroll
    for (int k = 0; k < 2; ++k) {
        load8(df + b * HH + hc * 8 + 128 * k, dfv + 8 * k);
        load8(v + hc * 8 + 128 * k, vv + 8 * k);
        load8(wc + hc * 8 + 128 * k, wcv + 8 * k);
    }

    const uint4* ep0 = encb + (size_t)(b * LL + l0 + lsub) * 32 + hc;

    auto scal = [&](int mi, float& cv, float& msk) {
        const int l = l0 + mi * 4 + lsub;
        const int idx = b * LL + l;
        msk = mask[idx];
        if (prev_t >= 0) {
            const float a = fexp(e_prev[idx] - Mprev) * msk * iSprev;
            cv = cov[idx] + a;
            if (hc == 0) {
                cov[idx] = cv;
                attns[((size_t)prev_t * BB + b) * LL + l] = a;
            }
        } else {
            cv = 0.f;
            if (hc == 0) cov[idx] = 0.f;
        }
    };

    float m = -INFINITY, s = 0.f;
    float cacc[16];
    #pragma unroll
    for (int j = 0; j < 16; ++j) cacc[j] = 0.f;

    float cvA, mskA;
    uint4 eA0, eA1;
    scal(0, cvA, mskA);
    eA0 = ep0[0]; eA1 = ep0[16];

    #pragma unroll
    for (int mi = 0; mi < LCHUNK / 16; ++mi) {   // 4 iterations
        float cvB = 0.f, mskB = 0.f;
        uint4 eB0 = {0,0,0,0}, eB1 = {0,0,0,0};
        if (mi < LCHUNK / 16 - 1) {
            scal(mi + 1, cvB, mskB);
            const uint4* epn = ep0 + (mi + 1) * 128;
            eB0 = epn[0]; eB1 = epn[16];
        }

        float fe[16];
        bf8x(eA0, fe); bf8x(eA1, fe + 8);
        float p = 0.f;
        #pragma unroll
        for (int j = 0; j < 16; ++j)
            p += vv[j] * ftanh(fe[j] + dfv[j] + cvA * wcv[j]);
        p += __shfl_xor(p, 1);
        p += __shfl_xor(p, 2);
        p += __shfl_xor(p, 4);
        p += __shfl_xor(p, 8);
        const int l = l0 + mi * 4 + lsub;
        if (hc == 0) e_cur[b * LL + l] = p;

        const float mn = fmaxf(m, p);
        const float sc = fexp(m - mn);
        const float w  = fexp(p - mn) * mskA;
        s = s * sc + w;
        #pragma unroll
        for (int j = 0; j < 16; ++j) cacc[j] = cacc[j] * sc + w * fe[j];
        m = mn;
        cvA = cvB; mskA = mskB; eA0 = eB0; eA1 = eB1;
    }

    // cross-subgroup butterfly (xor 16, 32) with max-rescale
    #pragma unroll
    for (int off = 16; off <= 32; off <<= 1) {
        const float m2 = __shfl_xor(m, off);
        const float s2 = __shfl_xor(s, off);
        const float mn = fmaxf(m, m2);
        const float wa = fexp(m - mn), wb = fexp(m2 - mn);
        s = s * wa + s2 * wb;
        #pragma unroll
        for (int j = 0; j < 16; ++j) {
            const float c2 = __shfl_xor(cacc[j], off);
            cacc[j] = cacc[j] * wa + c2 * wb;
        }
        m = mn;
    }

    __shared__ float lm[4], lsum[4];
    __shared__ float lctx[4][HH];
    if (lsub == 0) {
        #pragma unroll
        for (int k = 0; k < 2; ++k)
            #pragma unroll
            for (int j = 0; j < 8; ++j)
                lctx[wave][hc * 8 + 128 * k + j] = cacc[k * 8 + j];
    }
    if (lane == 0) { lm[wave] = m; lsum[wave] = s; }
    __syncthreads();

    const float M = fmaxf(fmaxf(lm[0], lm[1]), fmaxf(lm[2], lm[3]));
    const float w0 = fexp(lm[0] - M), w1 = fexp(lm[1] - M),
                w2 = fexp(lm[2] - M), w3 = fexp(lm[3] - M);
    const int pidx = chunk * BB + b;
    ctxp[(size_t)pidx * HH + tid] =
        lctx[0][tid] * w0 + lctx[1][tid] * w1 + lctx[2][tid] * w2 + lctx[3][tid] * w3;
    if (tid == 0) {
        mp[pidx] = M;
        sp[pidx] = lsum[0] * w0 + lsum[1] * w1 + lsum[2] * w2 + lsum[3] * w3;
    }
}

// ---------------------------------------------------------------------------
// K2: combine step-(t-1) attention partials -> ctx_{t-1} (+ m_ws/is_ws),
// then x_t = relu([inp_t, ctx_{t-1}] @ W_x + b_x). Grid BB, 256 threads.
// t == T_STEPS: final combine only.
// ---------------------------------------------------------------------------
__global__ __launch_bounds__(256) void ctx_x_kernel(
    const float* __restrict__ dec_in,
    const float* __restrict__ mp, const float* __restrict__ sp,
    const float* __restrict__ ctxp,
    const float* __restrict__ Wx, const float* __restrict__ bx,
    float* __restrict__ ctx_hist, float* __restrict__ x_hist,
    float* __restrict__ m_ws, float* __restrict__ is_ws, int t)
{
    const int b = blockIdx.x;
    const int tid = threadIdx.x;
    __shared__ float sctx[HH], siv[EE], xred[EE];

    if (t > 0) {
        float M = -INFINITY;
        #pragma unroll
        for (int k = 0; k < NCHUNK; ++k) M = fmaxf(M, mp[k * BB + b]);
        float S = 0.f, cs = 0.f;
        #pragma unroll
        for (int k = 0; k < NCHUNK; ++k) {
            const float w = fexp(mp[k * BB + b] - M);
            S += sp[k * BB + b] * w;
            cs += ctxp[(size_t)(k * BB + b) * HH + tid] * w;
        }
        const float invS = 1.f / S;
        sctx[tid] = cs * invS;
        ctx_hist[((size_t)(t - 1) * BB + b) * HH + tid] = sctx[tid];
        if (tid == 0) { m_ws[b] = M; is_ws[b] = invS; }
    } else {
        sctx[tid] = 0.f;
    }
    if (t < T_STEPS && tid < EE)
        siv[tid] = dec_in[((size_t)t * BB + b) * EE + tid];
    __syncthreads();

    if (t < T_STEPS) {
        const int j = tid & 127, q = tid >> 7;
        float a = 0.f;
        for (int r = q * 192; r < q * 192 + 192; ++r) {
            const float f = (r < EE) ? siv[r] : sctx[r - EE];
            a += f * Wx[(size_t)r * EE + j];
        }
        if (q) xred[j] = a;
        __syncthreads();
        if (!q)
            x_hist[((size_t)t * BB + b) * EE + j] = fmaxf(a + xred[j] + bx[j], 0.f);
    }
}

// ---------------------------------------------------------------------------
// K3: LSTM z-GEMM + (c,h) update for step t. Grid 512 blocks = (unit u,
// batch-half), 128 threads = 4 gates x 32 batches. Activations staged in
// LDS [32][385] (padded, conflict-free); weight cols [4][385].
// Reads c/h from hist[t-1] (or init), writes hist[t] -> no cross-block race.
// ---------------------------------------------------------------------------
__global__ __launch_bounds__(128) void lstm_kernel(
    const float* __restrict__ x_hist,
    const float* __restrict__ init_c, const float* __restrict__ init_h,
    const float* __restrict__ Wl, const float* __restrict__ bl,
    float* __restrict__ c_hist, float* __restrict__ h_hist, int t)
{
    const int u = blockIdx.x >> 1;
    const int half = blockIdx.x & 1;
    const int tid = threadIdx.x;
    __shared__ float f[32 * 385];
    __shared__ float wl[4 * 385];
    __shared__ float zs[4 * 32];

    const float* hsrc = (t == 0) ? init_h : (h_hist + (size_t)(t - 1) * BB * HH);
    const float* csrc = (t == 0) ? init_c : (c_hist + (size_t)(t - 1) * BB * HH);

    for (int i = tid; i < 32 * 128; i += 128) {
        const int mm = i >> 7, k = i & 127;
        f[mm * 385 + k] = x_hist[((size_t)t * BB + half * 32 + mm) * EE + k];
    }
    for (int i = tid; i < 32 * 256; i += 128) {
        const int mm = i >> 8, k = i & 255;
        f[mm * 385 + 128 + k] = hsrc[(half * 32 + mm) * HH + k];
    }
    for (int i = tid; i < 4 * 384; i += 128) {
        const int gg = i / 384, k = i - gg * 384;
        wl[gg * 385 + k] = Wl[(size_t)k * 1024 + gg * 256 + u];
    }
    __syncthreads();

    const int mm = tid & 31, gg = tid >> 5;
    float acc = bl[gg * 256 + u];
    const float* fr = f + mm * 385;
    const float* wr = wl + gg * 385;
    #pragma unroll 8
    for (int k = 0; k < 384; ++k) acc += fr[k] * wr[k];
    zs[gg * 32 + mm] = acc;
    __syncthreads();

    if (tid < 32) {
        const int mg = half * 32 + tid;
        const float zi = zs[tid], zf = zs[32 + tid], zg = zs[64 + tid], zo = zs[96 + tid];
        const float cp = csrc[mg * HH + u];
        const float cn = fsig(zf) * cp + fsig(zi) * ftanh(zg);
        const float hn = fsig(zo) * ftanh(cn);
        c_hist[((size_t)t * BB + mg) * HH + u] = cn;
        h_hist[((size_t)t * BB + mg) * HH + u] = hn;
    }
}

// ---------------------------------------------------------------------------
// K4: dec_feat_t = tanh([c_t, h_t] @ W_s + b_s). Grid BB, 512 threads.
// ---------------------------------------------------------------------------
__global__ __launch_bounds__(512) void df_kernel(
    const float* __restrict__ c_hist, const float* __restrict__ h_hist,
    const float* __restrict__ Ws, const float* __restrict__ bs,
    float* __restrict__ df_ws, int t)
{
    const int b = blockIdx.x;
    const int tid = threadIdx.x;
    __shared__ float sf[512];
    __shared__ float rbuf[256];
    sf[tid] = (tid < 256) ? c_hist[((size_t)t * BB + b) * HH + tid]
                          : h_hist[((size_t)t * BB + b) * HH + tid - 256];
    __syncthreads();
    const int j = tid & 255, half = tid >> 8;
    float a = 0.f;
    const float* wcol = Ws + (size_t)(half * 256) * HH + j;
    const float* src = sf + half * 256;
    #pragma unroll 4
    for (int r = 0; r < 256; ++r) a += src[r] * wcol[(size_t)r * HH];
    if (half) rbuf[j] = a;
    __syncthreads();
    if (!half) df_ws[b * HH + j] = ftanh(a + rbuf[j] + bs[j]);
}

// ---------------------------------------------------------------------------
// K5: epilogue for the last step: attns[T-1], final cov, and c/h outputs.
// Grid BB, 256 threads.
// ---------------------------------------------------------------------------
__global__ __launch_bounds__(256) void epi_kernel(
    const float* __restrict__ e_ws, const float* __restrict__ mask,
    const float* __restrict__ m_ws, const float* __restrict__ is_ws,
    const float* __restrict__ c_hist, const float* __restrict__ h_hist,
    float* __restrict__ attns, float* __restrict__ cov,
    float* __restrict__ c_out, float* __restrict__ h_out)
{
    const int b = blockIdx.x;
    const int j = threadIdx.x;
    const float Mp = m_ws[b], iS = is_ws[b];
    const float* e_last = e_ws + (size_t)((T_STEPS - 1) & 1) * BB * LL;
    for (int i = 0; i < LL / 256; ++i) {
        const int l = i * 256 + j;
        const int idx = b * LL + l;
        const float a = fexp(e_last[idx] - Mp) * mask[idx] * iS;
        attns[((size_t)(T_STEPS - 1) * BB + b) * LL + l] = a;
        cov[idx] += a;
    }
    c_out[b * HH + j] = c_hist[((size_t)(T_STEPS - 1) * BB + b) * HH + j];
    h_out[b * HH + j] = h_hist[((size_t)(T_STEPS - 1) * BB + b) * HH + j];
}

// ---------------------------------------------------------------------------
// K6: batched outs + pgens over all (t,b). Grid 256 blocks = (t, b-quarter),
// 256 threads. outs = [h,ctx]@W_o + b_o; pgen = sig([ctx,c,h,x]@W_p + b_p).
// ---------------------------------------------------------------------------
__global__ __launch_bounds__(256) void out_kernel(
    const float* __restrict__ h_hist, const float* __restrict__ ctx_hist,
    const float* __restrict__ c_hist, const float* __restrict__ x_hist,
    const float* __restrict__ Wo, const float* __restrict__ bo,
    const float* __restrict__ Wp, const float* __restrict__ bp,
    float* __restrict__ outs, float* __restrict__ pgens)
{
    const int t = blockIdx.x >> 2;
    const int bq = blockIdx.x & 3;
    const int tid = threadIdx.x;
    __shared__ float hs[16 * 256], cts[16 * 256], cs2[16 * 256], xs[16 * 128];

    for (int i = tid; i < 16 * 256; i += 256) {
        const int bl = i >> 8, j = i & 255;
        const size_t row = ((size_t)t * BB + bq * 16 + bl) * HH;
        hs[i] = h_hist[row + j];
        cts[i] = ctx_hist[row + j];
        cs2[i] = c_hist[row + j];
    }
    for (int i = tid; i < 16 * 128; i += 256) {
        const int bl = i >> 7, j = i & 127;
        xs[i] = x_hist[((size_t)t * BB + bq * 16 + bl) * EE + j];
    }
    __syncthreads();

    const int j = tid;
    float acc[16];
    #pragma unroll
    for (int bl = 0; bl < 16; ++bl) acc[bl] = 0.f;
    for (int r = 0; r < 256; ++r) {
        const float w0 = Wo[(size_t)r * HH + j];
        const float w1 = Wo[(size_t)(256 + r) * HH + j];
        #pragma unroll
        for (int bl = 0; bl < 16; ++bl)
            acc[bl] += hs[bl * 256 + r] * w0 + cts[bl * 256 + r] * w1;
    }
    #pragma unroll
    for (int bl = 0; bl < 16; ++bl)
        outs[((size_t)t * BB + bq * 16 + bl) * HH + j] = acc[bl] + bo[j];

    // pgens: 16 threads per batch row
    const int bl = tid >> 4, r16 = tid & 15;
    float p = 0.f;
    for (int i = r16; i < 256; i += 16)
        p += cts[bl * 256 + i] * Wp[i] + cs2[bl * 256 + i] * Wp[256 + i]
           + hs[bl * 256 + i] * Wp[512 + i];
    for (int i = r16; i < 128; i += 16)
        p += xs[bl * 128 + i] * Wp[768 + i];
    p += __shfl_xor(p, 1);
    p += __shfl_xor(p, 2);
    p += __shfl_xor(p, 4);
    p += __shfl_xor(p, 8);
    if (r16 == 0)
        pgens[(size_t)t * BB + bq * 16 + bl] = fsig(p + bp[0]);
}

extern "C" void kernel_launch(void* const* d_in, const int* in_sizes, int n_in,
                              void* d_out, int out_size, void* d_ws, size_t ws_size,
                              hipStream_t stream) {
    const float* dec_in = (const float*)d_in[0];
    const float* init_c = (const float*)d_in[1];
    const float* init_h = (const float*)d_in[2];
    const float* enc    = (const float*)d_in[3];
    const float* mask   = (const float*)d_in[4];
    const float* Wx = (const float*)d_in[5];
    const float* bx = (const float*)d_in[6];
    const float* Wl = (const float*)d_in[7];
    const float* bl = (const float*)d_in[8];
    const float* Ws = (const float*)d_in[9];
    const float* bs = (const float*)d_in[10];
    const float* v  = (const float*)d_in[11];
    const float* wc = (const float*)d_in[12];
    const float* Wp = (const float*)d_in[13];
    const float* bp = (const float*)d_in[14];
    const float* Wo = (const float*)d_in[15];
    const float* bo = (const float*)d_in[16];

    float* out   = (float*)d_out;
    float* outs  = out;                                   // T*B*H
    float* c_out = outs + (size_t)T_STEPS * BB * HH;      // B*H
    float* h_out = c_out + BB * HH;                       // B*H
    float* attns = h_out + BB * HH;                       // T*B*L
    float* pgens = attns + (size_t)T_STEPS * BB * LL;     // T*B
    float* cov   = pgens + T_STEPS * BB;                  // B*L

    float* ws     = (float*)d_ws;
    uint4* encb   = (uint4*)ws;                           // B*L*H bf16 = 16.78M floats
    float* e_ws   = ws + (size_t)BB * LL * HH / 2;        // 2*B*L
    float* mp     = e_ws + 2 * BB * LL;                   // 32*B
    float* sp     = mp + NCHUNK * BB;                     // 32*B
    float* ctxp   = sp + NCHUNK * BB;                     // 32*B*H
    float* x_hist = ctxp + (size_t)NCHUNK * BB * HH;      // T*B*E
    float* df_ws  = x_hist + (size_t)T_STEPS * BB * EE;   // B*H
    float* m_ws   = df_ws + BB * HH;                      // B
    float* is_ws  = m_ws + BB;                            // B
    float* ctx_hist = is_ws + BB;                         // T*B*H
    float* c_hist = ctx_hist + (size_t)T_STEPS * BB * HH; // T*B*H
    float* h_hist = c_hist + (size_t)T_STEPS * BB * HH;   // T*B*H

    conv_kernel<<<4096, 256, 0, stream>>>((const float4*)enc, encb);

    for (int t = 0; t < T_STEPS; ++t) {
        ctx_x_kernel<<<BB, 256, 0, stream>>>(dec_in, mp, sp, ctxp, Wx, bx,
            ctx_hist, x_hist, m_ws, is_ws, t);
        lstm_kernel<<<512, 128, 0, stream>>>(x_hist, init_c, init_h, Wl, bl,
            c_hist, h_hist, t);
        df_kernel<<<BB, 512, 0, stream>>>(c_hist, h_hist, Ws, bs, df_ws, t);
        attn_kernel<<<NCHUNK * BB, 256, 0, stream>>>(encb, mask, cov, df_ws,
            v, wc, e_ws, attns, m_ws, is_ws, mp, sp, ctxp, t);
    }
    // final combine (ctx_{T-1}, m/is for last attns)
    ctx_x_kernel<<<BB, 256, 0, stream>>>(dec_in, mp, sp, ctxp, Wx, bx,
        ctx_hist, x_hist, m_ws, is_ws, T_STEPS);
    epi_kernel<<<BB, 256, 0, stream>>>(e_ws, mask, m_ws, is_ws,
        c_hist, h_hist, attns, cov, c_out, h_out);
    out_kernel<<<256, 256, 0, stream>>>(h_hist, ctx_hist, c_hist, x_hist,
        Wo, bo, Wp, bp, outs, pgens);
}